// Round 1
// baseline (589.032 us; speedup 1.0000x reference)
//
#include <hip/hip_runtime.h>
#include <hip/hip_bf16.h>
#include <stdint.h>

// ---------------------------------------------------------------------------
// TrafficGNN: 2-layer GCN + skip, N=50000, E=1.6M, dims 256->128->128.
// Pipeline:
//   deg (int atomics) -> scan (row_start, dinv=rsqrt(deg+1)) -> CSR scatter
//   scaled1 = (x@W1)*dinv        [MFMA bf16, epilogue scale, bf16 store]
//   h1 = relu(dinv*(gather-sum scaled1 + self) + b1)        [CSR gather]
//   scaled2 = (h1@W2)*dinv
//   h2 = relu(dinv*(gather-sum scaled2 + self) + b2)
//   out = x@Ws + (bs+bf)         [f32 store]
//   out += h2@Wf                 [f32 RMW]
// ---------------------------------------------------------------------------

typedef __attribute__((ext_vector_type(8))) short bf16x8;
typedef __attribute__((ext_vector_type(4))) float f32x4;

__device__ __forceinline__ short f2bf(float f) {
  uint32_t u = __float_as_uint(f);
  u += 0x7fffu + ((u >> 16) & 1u);   // round-to-nearest-even
  return (short)(u >> 16);
}

// --- degree histogram (int atomics; deterministic counts) -------------------
__global__ void k_deg(const int* __restrict__ dst, int* __restrict__ deg, int E) {
  int i = blockIdx.x * blockDim.x + threadIdx.x;
  if (i < E) atomicAdd(&deg[dst[i]], 1);
}

// --- weight transpose + cast: W[K][N] f32 -> WT[N][K] bf16 ------------------
__global__ void k_wt(const float* __restrict__ W, short* __restrict__ WT, int K, int N) {
  int i = blockIdx.x * blockDim.x + threadIdx.x;
  if (i >= K * N) return;
  int k = i / N, n = i - k * N;
  WT[(size_t)n * K + k] = f2bf(W[i]);
}

// --- single-block scan: row_start = exclusive prefix of deg; dinv -----------
__global__ __launch_bounds__(1024) void k_scan(const int* __restrict__ deg,
                                               float* __restrict__ dinv,
                                               int* __restrict__ row_start, int n) {
  __shared__ int sums[1024];
  int t = threadIdx.x;
  int C = (n + 1023) >> 10;
  int base = t * C;
  int local = 0;
  for (int i = 0; i < C; ++i) { int idx = base + i; if (idx < n) local += deg[idx]; }
  sums[t] = local;
  __syncthreads();
  for (int off = 1; off < 1024; off <<= 1) {
    int v = (t >= off) ? sums[t - off] : 0;
    __syncthreads();
    sums[t] += v;
    __syncthreads();
  }
  int run = (t == 0) ? 0 : sums[t - 1];
  for (int i = 0; i < C; ++i) {
    int idx = base + i;
    if (idx < n) {
      row_start[idx] = run;
      int d = deg[idx];
      run += d;
      dinv[idx] = rsqrtf((float)(d + 1));   // +1 self-loop
    }
  }
  if (t == 1023) row_start[n] = sums[1023];
}

// --- CSR scatter ------------------------------------------------------------
__global__ void k_csr(const int* __restrict__ src, const int* __restrict__ dst,
                      const int* __restrict__ row_start, int* __restrict__ cursor,
                      int* __restrict__ csr_src, int E) {
  int i = blockIdx.x * blockDim.x + threadIdx.x;
  if (i < E) {
    int d = dst[i];
    int p = atomicAdd(&cursor[d], 1);
    csr_src[row_start[d] + p] = src[i];
  }
}

// --- MFMA GEMM: [M,K] @ WT[N=128,K] -> epilogue variants --------------------
// wave computes 16 rows x 128 cols; block = 4 waves = 64 rows.
// A-frag: lane holds A[rowBase + (lane&15)][k0 + 8*(lane>>4) + 0..7]
// B-frag (col tile c): lane holds B[k...][c*16 + (lane&15)] via WT row read
// D: col = lane&15 (within tile), row = (lane>>4)*4 + reg   [m89-verified]
enum { EPI_SCALE = 0, EPI_BIAS2 = 1, EPI_ADD = 2 };

template <bool A_F32, int K, int EPI>
__global__ __launch_bounds__(256) void k_gemm(const void* __restrict__ Av,
                                              const short* __restrict__ BT,
                                              const float* __restrict__ aux1,
                                              const float* __restrict__ aux2,
                                              void* __restrict__ outv, int M) {
  int wave = threadIdx.x >> 6;
  int lane = threadIdx.x & 63;
  int rowBase = (blockIdx.x * 4 + wave) * 16;
  if (rowBase >= M) return;           // M % 16 == 0, tiles fully valid or absent
  int r = lane & 15;
  int g = lane >> 4;
  int row = rowBase + r;

  f32x4 acc[8];
#pragma unroll
  for (int c = 0; c < 8; ++c) acc[c] = f32x4{0.f, 0.f, 0.f, 0.f};

  for (int k0 = 0; k0 < K; k0 += 32) {
    int kk = k0 + g * 8;
    bf16x8 afrag;
    if constexpr (A_F32) {
      const float* A = (const float*)Av;
      const f32x4* p = (const f32x4*)(A + (size_t)row * K + kk);
      f32x4 v0 = p[0], v1 = p[1];
      afrag[0] = f2bf(v0[0]); afrag[1] = f2bf(v0[1]);
      afrag[2] = f2bf(v0[2]); afrag[3] = f2bf(v0[3]);
      afrag[4] = f2bf(v1[0]); afrag[5] = f2bf(v1[1]);
      afrag[6] = f2bf(v1[2]); afrag[7] = f2bf(v1[3]);
    } else {
      const short* A = (const short*)Av;
      afrag = *(const bf16x8*)(A + (size_t)row * K + kk);
    }
#pragma unroll
    for (int c = 0; c < 8; ++c) {
      bf16x8 bfrag = *(const bf16x8*)(BT + (size_t)(c * 16 + r) * K + kk);
      acc[c] = __builtin_amdgcn_mfma_f32_16x16x32_bf16(afrag, bfrag, acc[c], 0, 0, 0);
    }
  }

#pragma unroll
  for (int c = 0; c < 8; ++c) {
    int cc = c * 16 + r;
#pragma unroll
    for (int j = 0; j < 4; ++j) {
      int rr = rowBase + g * 4 + j;
      float v = acc[c][j];
      if constexpr (EPI == EPI_SCALE) {
        ((short*)outv)[(size_t)rr * 128 + cc] = f2bf(v * aux1[rr]);
      } else if constexpr (EPI == EPI_BIAS2) {
        ((float*)outv)[(size_t)rr * 128 + cc] = v + aux1[cc] + aux2[cc];
      } else {
        float* o = (float*)outv + (size_t)rr * 128 + cc;
        *o += v;
      }
    }
  }
}

// --- per-node CSR gather-aggregate: 1 wave per node, 2 bf16 cols per lane ---
__global__ __launch_bounds__(256) void k_aggregate(const short* __restrict__ scaled,
                                                   const float* __restrict__ dinv,
                                                   const float* __restrict__ bias,
                                                   const int* __restrict__ row_start,
                                                   const int* __restrict__ csr_src,
                                                   short* __restrict__ hout, int n) {
  int node = blockIdx.x * 4 + (threadIdx.x >> 6);
  if (node >= n) return;
  int lane = threadIdx.x & 63;

  uint32_t u = ((const uint32_t*)(scaled + (size_t)node * 128))[lane];  // self loop
  float s0 = __uint_as_float(u << 16);
  float s1 = __uint_as_float(u & 0xffff0000u);

  int beg = row_start[node], end = row_start[node + 1];
  int j = beg;
  for (; j + 2 <= end; j += 2) {          // 2-wide for gather latency overlap
    int a = csr_src[j], b = csr_src[j + 1];
    uint32_t ua = ((const uint32_t*)(scaled + (size_t)a * 128))[lane];
    uint32_t ub = ((const uint32_t*)(scaled + (size_t)b * 128))[lane];
    s0 += __uint_as_float(ua << 16);
    s1 += __uint_as_float(ua & 0xffff0000u);
    s0 += __uint_as_float(ub << 16);
    s1 += __uint_as_float(ub & 0xffff0000u);
  }
  if (j < end) {
    int a = csr_src[j];
    uint32_t ua = ((const uint32_t*)(scaled + (size_t)a * 128))[lane];
    s0 += __uint_as_float(ua << 16);
    s1 += __uint_as_float(ua & 0xffff0000u);
  }

  float di = dinv[node];
  float h0 = fmaxf(fmaf(s0, di, bias[lane * 2]), 0.f);
  float h1 = fmaxf(fmaf(s1, di, bias[lane * 2 + 1]), 0.f);
  uint32_t o = (uint32_t)(uint16_t)f2bf(h0) | ((uint32_t)(uint16_t)f2bf(h1) << 16);
  ((uint32_t*)(hout + (size_t)node * 128))[lane] = o;
}

extern "C" void kernel_launch(void* const* d_in, const int* in_sizes, int n_in,
                              void* d_out, int out_size, void* d_ws, size_t ws_size,
                              hipStream_t stream) {
  const float* x  = (const float*)d_in[0];
  const int* ei   = (const int*)d_in[1];
  const float* W1 = (const float*)d_in[2];
  const float* b1 = (const float*)d_in[3];
  const float* W2 = (const float*)d_in[4];
  const float* b2 = (const float*)d_in[5];
  const float* Wsk = (const float*)d_in[6];
  const float* bsk = (const float*)d_in[7];
  const float* Wf = (const float*)d_in[8];
  const float* bf_ = (const float*)d_in[9];

  const int n = in_sizes[0] / 256;
  const int E = in_sizes[1] / 2;
  const int* src = ei;
  const int* dst = ei + E;

  char* p = (char*)d_ws;
  auto alloc = [&](size_t bytes) -> char* {
    char* r = p;
    p += (bytes + 255) & ~(size_t)255;
    return r;
  };
  short* scaled    = (short*)alloc((size_t)n * 128 * 2);  // 12.8 MB
  short* hbuf      = (short*)alloc((size_t)n * 128 * 2);  // 12.8 MB
  int* csr_src     = (int*)alloc((size_t)E * 4);          // 6.4 MB
  int* deg         = (int*)alloc((size_t)n * 4);
  int* cursor      = (int*)alloc((size_t)n * 4);
  int* row_start   = (int*)alloc((size_t)(n + 1) * 4);
  float* dinv      = (float*)alloc((size_t)n * 4);
  short* W1T       = (short*)alloc(256 * 128 * 2);
  short* W2T       = (short*)alloc(128 * 128 * 2);
  short* WsT       = (short*)alloc(256 * 128 * 2);
  short* WfT       = (short*)alloc(128 * 128 * 2);

  hipMemsetAsync(deg, 0, (size_t)n * 4, stream);
  hipMemsetAsync(cursor, 0, (size_t)n * 4, stream);

  const int tb = 256;
  k_deg<<<(E + tb - 1) / tb, tb, 0, stream>>>(dst, deg, E);
  k_wt<<<(256 * 128 + tb - 1) / tb, tb, 0, stream>>>(W1, W1T, 256, 128);
  k_wt<<<(128 * 128 + tb - 1) / tb, tb, 0, stream>>>(W2, W2T, 128, 128);
  k_wt<<<(256 * 128 + tb - 1) / tb, tb, 0, stream>>>(Wsk, WsT, 256, 128);
  k_wt<<<(128 * 128 + tb - 1) / tb, tb, 0, stream>>>(Wf, WfT, 128, 128);
  k_scan<<<1, 1024, 0, stream>>>(deg, dinv, row_start, n);
  k_csr<<<(E + tb - 1) / tb, tb, 0, stream>>>(src, dst, row_start, cursor, csr_src, E);

  const int gblocks = (n + 63) / 64;
  // layer 1
  k_gemm<true, 256, EPI_SCALE><<<gblocks, 256, 0, stream>>>(x, W1T, dinv, nullptr, scaled, n);
  k_aggregate<<<(n + 3) / 4, 256, 0, stream>>>(scaled, dinv, b1, row_start, csr_src, hbuf, n);
  // layer 2
  k_gemm<false, 128, EPI_SCALE><<<gblocks, 256, 0, stream>>>(hbuf, W2T, dinv, nullptr, scaled, n);
  k_aggregate<<<(n + 3) / 4, 256, 0, stream>>>(scaled, dinv, b2, row_start, csr_src, hbuf, n);
  // skip + final
  k_gemm<true, 256, EPI_BIAS2><<<gblocks, 256, 0, stream>>>(x, WsT, bsk, bf_, d_out, n);
  k_gemm<false, 128, EPI_ADD><<<gblocks, 256, 0, stream>>>(hbuf, WfT, nullptr, nullptr, d_out, n);
}

// Round 2
// 469.281 us; speedup vs baseline: 1.2552x; 1.2552x over previous
//
#include <hip/hip_runtime.h>
#include <hip/hip_bf16.h>
#include <stdint.h>

// ---------------------------------------------------------------------------
// TrafficGNN: 2-layer GCN + skip, N=50000, E=1.6M, dims 256->128->128.
// R2 changes vs R1:
//  - k_scan (single-block, 122us, 21% of total) -> 3-stage hierarchical scan
//    (k_blocksum / k_scan_partials / k_scan_final), ~10us total.
//  - final two GEMMs (x@Ws store + h2@Wf RMW) fused into k_gemm_dual:
//    one accumulator, one store; saves ~51MB of d_out traffic.
// ---------------------------------------------------------------------------

typedef __attribute__((ext_vector_type(8))) short bf16x8;
typedef __attribute__((ext_vector_type(4))) float f32x4;

__device__ __forceinline__ short f2bf(float f) {
  uint32_t u = __float_as_uint(f);
  u += 0x7fffu + ((u >> 16) & 1u);   // round-to-nearest-even
  return (short)(u >> 16);
}

// --- degree histogram (int atomics; deterministic counts) -------------------
__global__ void k_deg(const int* __restrict__ dst, int* __restrict__ deg, int E) {
  int i = blockIdx.x * blockDim.x + threadIdx.x;
  if (i < E) atomicAdd(&deg[dst[i]], 1);
}

// --- weight transpose + cast: W[K][N] f32 -> WT[N][K] bf16 ------------------
__global__ void k_wt(const float* __restrict__ W, short* __restrict__ WT, int K, int N) {
  int i = blockIdx.x * blockDim.x + threadIdx.x;
  if (i >= K * N) return;
  int k = i / N, n = i - k * N;
  WT[(size_t)n * K + k] = f2bf(W[i]);
}

// --- hierarchical scan stage 1: per-block sums of deg -----------------------
__global__ __launch_bounds__(256) void k_blocksum(const int* __restrict__ deg,
                                                  int* __restrict__ partials, int n) {
  __shared__ int s[256];
  int t = threadIdx.x;
  int idx = blockIdx.x * 256 + t;
  s[t] = (idx < n) ? deg[idx] : 0;
  __syncthreads();
  for (int off = 128; off; off >>= 1) {
    if (t < off) s[t] += s[t + off];
    __syncthreads();
  }
  if (t == 0) partials[blockIdx.x] = s[0];
}

// --- stage 2: single tiny block scans the partials (nb <= 256) --------------
__global__ __launch_bounds__(256) void k_scan_partials(int* __restrict__ partials, int nb) {
  __shared__ int s[256];
  int t = threadIdx.x;
  int v = (t < nb) ? partials[t] : 0;
  s[t] = v;
  __syncthreads();
  for (int off = 1; off < 256; off <<= 1) {
    int u = (t >= off) ? s[t - off] : 0;
    __syncthreads();
    s[t] += u;
    __syncthreads();
  }
  if (t < nb) partials[t] = s[t] - v;   // exclusive
}

// --- stage 3: local exclusive scan + block offset; also dinv ----------------
__global__ __launch_bounds__(256) void k_scan_final(const int* __restrict__ deg,
                                                    const int* __restrict__ boff,
                                                    int* __restrict__ row_start,
                                                    float* __restrict__ dinv, int n) {
  __shared__ int s[256];
  int t = threadIdx.x;
  int idx = blockIdx.x * 256 + t;
  int d = (idx < n) ? deg[idx] : 0;
  s[t] = d;
  __syncthreads();
  for (int off = 1; off < 256; off <<= 1) {
    int u = (t >= off) ? s[t - off] : 0;
    __syncthreads();
    s[t] += u;
    __syncthreads();
  }
  int incl = s[t];
  int base = boff[blockIdx.x];
  if (idx < n) {
    row_start[idx] = base + incl - d;
    dinv[idx] = rsqrtf((float)(d + 1));   // +1 self-loop
    if (idx == n - 1) row_start[n] = base + incl;
  }
}

// --- CSR scatter ------------------------------------------------------------
__global__ void k_csr(const int* __restrict__ src, const int* __restrict__ dst,
                      const int* __restrict__ row_start, int* __restrict__ cursor,
                      int* __restrict__ csr_src, int E) {
  int i = blockIdx.x * blockDim.x + threadIdx.x;
  if (i < E) {
    int d = dst[i];
    int p = atomicAdd(&cursor[d], 1);
    csr_src[row_start[d] + p] = src[i];
  }
}

// --- MFMA GEMM: [M,K] @ WT[N=128,K] -> epilogue variants --------------------
// wave computes 16 rows x 128 cols; block = 4 waves = 64 rows.
// D layout (m89-verified): col = lane&15, row = (lane>>4)*4 + reg.
enum { EPI_SCALE = 0 };

template <bool A_F32, int K, int EPI>
__global__ __launch_bounds__(256) void k_gemm(const void* __restrict__ Av,
                                              const short* __restrict__ BT,
                                              const float* __restrict__ aux1,
                                              void* __restrict__ outv, int M) {
  int wave = threadIdx.x >> 6;
  int lane = threadIdx.x & 63;
  int rowBase = (blockIdx.x * 4 + wave) * 16;
  if (rowBase >= M) return;
  int r = lane & 15;
  int g = lane >> 4;
  int row = rowBase + r;

  f32x4 acc[8];
#pragma unroll
  for (int c = 0; c < 8; ++c) acc[c] = f32x4{0.f, 0.f, 0.f, 0.f};

  for (int k0 = 0; k0 < K; k0 += 32) {
    int kk = k0 + g * 8;
    bf16x8 afrag;
    if constexpr (A_F32) {
      const float* A = (const float*)Av;
      const f32x4* p = (const f32x4*)(A + (size_t)row * K + kk);
      f32x4 v0 = p[0], v1 = p[1];
      afrag[0] = f2bf(v0[0]); afrag[1] = f2bf(v0[1]);
      afrag[2] = f2bf(v0[2]); afrag[3] = f2bf(v0[3]);
      afrag[4] = f2bf(v1[0]); afrag[5] = f2bf(v1[1]);
      afrag[6] = f2bf(v1[2]); afrag[7] = f2bf(v1[3]);
    } else {
      const short* A = (const short*)Av;
      afrag = *(const bf16x8*)(A + (size_t)row * K + kk);
    }
#pragma unroll
    for (int c = 0; c < 8; ++c) {
      bf16x8 bfrag = *(const bf16x8*)(BT + (size_t)(c * 16 + r) * K + kk);
      acc[c] = __builtin_amdgcn_mfma_f32_16x16x32_bf16(afrag, bfrag, acc[c], 0, 0, 0);
    }
  }

#pragma unroll
  for (int c = 0; c < 8; ++c) {
    int cc = c * 16 + r;
#pragma unroll
    for (int j = 0; j < 4; ++j) {
      int rr = rowBase + g * 4 + j;
      ((short*)outv)[(size_t)rr * 128 + cc] = f2bf(acc[c][j] * aux1[rr]);
    }
  }
}

// --- fused final: out = x@WsT + h2@WfT + (bs+bf) ----------------------------
template <int K1, int K2>
__global__ __launch_bounds__(256) void k_gemm_dual(const float* __restrict__ A1,
                                                   const short* __restrict__ B1T,
                                                   const short* __restrict__ A2,
                                                   const short* __restrict__ B2T,
                                                   const float* __restrict__ bias1,
                                                   const float* __restrict__ bias2,
                                                   float* __restrict__ out, int M) {
  int wave = threadIdx.x >> 6;
  int lane = threadIdx.x & 63;
  int rowBase = (blockIdx.x * 4 + wave) * 16;
  if (rowBase >= M) return;
  int r = lane & 15;
  int g = lane >> 4;
  int row = rowBase + r;

  f32x4 acc[8];
#pragma unroll
  for (int c = 0; c < 8; ++c) acc[c] = f32x4{0.f, 0.f, 0.f, 0.f};

  for (int k0 = 0; k0 < K1; k0 += 32) {
    int kk = k0 + g * 8;
    const f32x4* p = (const f32x4*)(A1 + (size_t)row * K1 + kk);
    f32x4 v0 = p[0], v1 = p[1];
    bf16x8 afrag;
    afrag[0] = f2bf(v0[0]); afrag[1] = f2bf(v0[1]);
    afrag[2] = f2bf(v0[2]); afrag[3] = f2bf(v0[3]);
    afrag[4] = f2bf(v1[0]); afrag[5] = f2bf(v1[1]);
    afrag[6] = f2bf(v1[2]); afrag[7] = f2bf(v1[3]);
#pragma unroll
    for (int c = 0; c < 8; ++c) {
      bf16x8 bfrag = *(const bf16x8*)(B1T + (size_t)(c * 16 + r) * K1 + kk);
      acc[c] = __builtin_amdgcn_mfma_f32_16x16x32_bf16(afrag, bfrag, acc[c], 0, 0, 0);
    }
  }
  for (int k0 = 0; k0 < K2; k0 += 32) {
    int kk = k0 + g * 8;
    bf16x8 afrag = *(const bf16x8*)(A2 + (size_t)row * K2 + kk);
#pragma unroll
    for (int c = 0; c < 8; ++c) {
      bf16x8 bfrag = *(const bf16x8*)(B2T + (size_t)(c * 16 + r) * K2 + kk);
      acc[c] = __builtin_amdgcn_mfma_f32_16x16x32_bf16(afrag, bfrag, acc[c], 0, 0, 0);
    }
  }

#pragma unroll
  for (int c = 0; c < 8; ++c) {
    int cc = c * 16 + r;
    float b = bias1[cc] + bias2[cc];
#pragma unroll
    for (int j = 0; j < 4; ++j) {
      int rr = rowBase + g * 4 + j;
      out[(size_t)rr * 128 + cc] = acc[c][j] + b;
    }
  }
}

// --- per-node CSR gather-aggregate: 1 wave per node, 2 bf16 cols per lane ---
__global__ __launch_bounds__(256) void k_aggregate(const short* __restrict__ scaled,
                                                   const float* __restrict__ dinv,
                                                   const float* __restrict__ bias,
                                                   const int* __restrict__ row_start,
                                                   const int* __restrict__ csr_src,
                                                   short* __restrict__ hout, int n) {
  int node = blockIdx.x * 4 + (threadIdx.x >> 6);
  if (node >= n) return;
  int lane = threadIdx.x & 63;

  uint32_t u = ((const uint32_t*)(scaled + (size_t)node * 128))[lane];  // self loop
  float s0 = __uint_as_float(u << 16);
  float s1 = __uint_as_float(u & 0xffff0000u);

  int beg = row_start[node], end = row_start[node + 1];
  int j = beg;
  for (; j + 2 <= end; j += 2) {
    int a = csr_src[j], b = csr_src[j + 1];
    uint32_t ua = ((const uint32_t*)(scaled + (size_t)a * 128))[lane];
    uint32_t ub = ((const uint32_t*)(scaled + (size_t)b * 128))[lane];
    s0 += __uint_as_float(ua << 16);
    s1 += __uint_as_float(ua & 0xffff0000u);
    s0 += __uint_as_float(ub << 16);
    s1 += __uint_as_float(ub & 0xffff0000u);
  }
  if (j < end) {
    int a = csr_src[j];
    uint32_t ua = ((const uint32_t*)(scaled + (size_t)a * 128))[lane];
    s0 += __uint_as_float(ua << 16);
    s1 += __uint_as_float(ua & 0xffff0000u);
  }

  float di = dinv[node];
  float h0 = fmaxf(fmaf(s0, di, bias[lane * 2]), 0.f);
  float h1 = fmaxf(fmaf(s1, di, bias[lane * 2 + 1]), 0.f);
  uint32_t o = (uint32_t)(uint16_t)f2bf(h0) | ((uint32_t)(uint16_t)f2bf(h1) << 16);
  ((uint32_t*)(hout + (size_t)node * 128))[lane] = o;
}

extern "C" void kernel_launch(void* const* d_in, const int* in_sizes, int n_in,
                              void* d_out, int out_size, void* d_ws, size_t ws_size,
                              hipStream_t stream) {
  const float* x  = (const float*)d_in[0];
  const int* ei   = (const int*)d_in[1];
  const float* W1 = (const float*)d_in[2];
  const float* b1 = (const float*)d_in[3];
  const float* W2 = (const float*)d_in[4];
  const float* b2 = (const float*)d_in[5];
  const float* Wsk = (const float*)d_in[6];
  const float* bsk = (const float*)d_in[7];
  const float* Wf = (const float*)d_in[8];
  const float* bf_ = (const float*)d_in[9];

  const int n = in_sizes[0] / 256;
  const int E = in_sizes[1] / 2;
  const int* src = ei;
  const int* dst = ei + E;

  char* p = (char*)d_ws;
  auto alloc = [&](size_t bytes) -> char* {
    char* r = p;
    p += (bytes + 255) & ~(size_t)255;
    return r;
  };
  short* scaled    = (short*)alloc((size_t)n * 128 * 2);  // 12.8 MB
  short* hbuf      = (short*)alloc((size_t)n * 128 * 2);  // 12.8 MB
  int* csr_src     = (int*)alloc((size_t)E * 4);          // 6.4 MB
  int* deg         = (int*)alloc((size_t)n * 4);
  int* cursor      = (int*)alloc((size_t)n * 4);
  int* row_start   = (int*)alloc((size_t)(n + 1) * 4);
  float* dinv      = (float*)alloc((size_t)n * 4);
  int* partials    = (int*)alloc(256 * 4);
  short* W1T       = (short*)alloc(256 * 128 * 2);
  short* W2T       = (short*)alloc(128 * 128 * 2);
  short* WsT       = (short*)alloc(256 * 128 * 2);
  short* WfT       = (short*)alloc(128 * 128 * 2);

  hipMemsetAsync(deg, 0, (size_t)n * 4, stream);
  hipMemsetAsync(cursor, 0, (size_t)n * 4, stream);

  const int tb = 256;
  const int nb = (n + 255) / 256;   // 196 scan blocks (<= 256)
  k_deg<<<(E + tb - 1) / tb, tb, 0, stream>>>(dst, deg, E);
  k_wt<<<(256 * 128 + tb - 1) / tb, tb, 0, stream>>>(W1, W1T, 256, 128);
  k_wt<<<(128 * 128 + tb - 1) / tb, tb, 0, stream>>>(W2, W2T, 128, 128);
  k_wt<<<(256 * 128 + tb - 1) / tb, tb, 0, stream>>>(Wsk, WsT, 256, 128);
  k_wt<<<(128 * 128 + tb - 1) / tb, tb, 0, stream>>>(Wf, WfT, 128, 128);
  k_blocksum<<<nb, 256, 0, stream>>>(deg, partials, n);
  k_scan_partials<<<1, 256, 0, stream>>>(partials, nb);
  k_scan_final<<<nb, 256, 0, stream>>>(deg, partials, row_start, dinv, n);
  k_csr<<<(E + tb - 1) / tb, tb, 0, stream>>>(src, dst, row_start, cursor, csr_src, E);

  const int gblocks = (n + 63) / 64;
  // layer 1
  k_gemm<true, 256, EPI_SCALE><<<gblocks, 256, 0, stream>>>(x, W1T, dinv, scaled, n);
  k_aggregate<<<(n + 3) / 4, 256, 0, stream>>>(scaled, dinv, b1, row_start, csr_src, hbuf, n);
  // layer 2
  k_gemm<false, 128, EPI_SCALE><<<gblocks, 256, 0, stream>>>(hbuf, W2T, dinv, scaled, n);
  k_aggregate<<<(n + 3) / 4, 256, 0, stream>>>(scaled, dinv, b2, row_start, csr_src, hbuf, n);
  // fused skip + final
  k_gemm_dual<256, 128><<<gblocks, 256, 0, stream>>>(x, WsT, hbuf, WfT, bsk, bf_, (float*)d_out, n);
}

// Round 3
// 299.052 us; speedup vs baseline: 1.9697x; 1.5692x over previous
//
#include <hip/hip_runtime.h>
#include <hip/hip_bf16.h>
#include <stdint.h>

// ---------------------------------------------------------------------------
// TrafficGNN: 2-layer GCN + skip, N=50000, E=1.6M, dims 256->128->128.
// R3 changes vs R2:
//  - k_deg + scans + k_csr (random 4B scatter, 102MB HBM writes, ~140us)
//    replaced by cache-aware counting sort:
//      k_count    : per-chunk LDS histogram over 512 dst-buckets
//      k_colscan  : per-bucket exclusive scan over chunks
//      k_btot_scan: bucket starts (+ row_start[n]=E)
//      k_scatter  : LDS multisplit + coalesced segment copy-out -> pair buffer
//      k_bucket2csr: per-bucket (single-owner 25KB window) -> csr_src,
//                    row_start, dinv  (absorbs k_deg + dinv work)
//  - 4x k_wt fused into k_wtall; memsets removed.
//  - pairs buffer aliases `scaled` (dead before GEMM-1 writes it).
//  - aggregate gather 2-wide -> 4-wide.
// ---------------------------------------------------------------------------

typedef __attribute__((ext_vector_type(8))) short bf16x8;
typedef __attribute__((ext_vector_type(4))) float f32x4;

#define NB 512        // dst buckets
#define NPB 98        // nodes per bucket (512*98 = 50176 >= 50000)
#define CHUNK 8192    // edges per k_count/k_scatter block
#define SUB 2048      // multisplit sub-chunk (LDS staging)

__device__ __forceinline__ short f2bf(float f) {
  uint32_t u = __float_as_uint(f);
  u += 0x7fffu + ((u >> 16) & 1u);   // round-to-nearest-even
  return (short)(u >> 16);
}

// --- fused weight transpose+cast: W[K][N] f32 -> WT[N][K] bf16 --------------
__global__ void k_wtall(const float* __restrict__ W1, const float* __restrict__ W2,
                        const float* __restrict__ Ws, const float* __restrict__ Wf,
                        short* __restrict__ W1T, short* __restrict__ W2T,
                        short* __restrict__ WsT, short* __restrict__ WfT) {
  int i = blockIdx.x * blockDim.x + threadIdx.x;
  const float* W; short* WT; int K, off;
  if (i < 32768)      { W = W1; WT = W1T; K = 256; off = 0; }
  else if (i < 49152) { W = W2; WT = W2T; K = 128; off = 32768; }
  else if (i < 81920) { W = Ws; WT = WsT; K = 256; off = 49152; }
  else if (i < 98304) { W = Wf; WT = WfT; K = 128; off = 81920; }
  else return;
  int j = i - off;
  int k = j >> 7, n = j & 127;            // N = 128 always
  WT[n * K + k] = f2bf(W[j]);
}

// --- stage 1: per-chunk bucket histogram ------------------------------------
__global__ __launch_bounds__(256) void k_count(const int* __restrict__ dst,
                                               int* __restrict__ count, int E) {
  __shared__ int h[NB];
  int t = threadIdx.x;
  for (int b = t; b < NB; b += 256) h[b] = 0;
  __syncthreads();
  int base = blockIdx.x * CHUNK;
  for (int i = t; i < CHUNK; i += 256) {
    int idx = base + i;
    if (idx < E) atomicAdd(&h[dst[idx] / NPB], 1);
  }
  __syncthreads();
  for (int b = t; b < NB; b += 256) count[blockIdx.x * NB + b] = h[b];
}

// --- stage 2: per-bucket exclusive scan over chunks (nblk <= 256) -----------
__global__ __launch_bounds__(256) void k_colscan(int* __restrict__ count,
                                                 int* __restrict__ btot, int nblk) {
  __shared__ int s[256];
  int t = threadIdx.x, b = blockIdx.x;
  int v = (t < nblk) ? count[t * NB + b] : 0;
  s[t] = v;
  __syncthreads();
  for (int off = 1; off < 256; off <<= 1) {
    int u = (t >= off) ? s[t - off] : 0;
    __syncthreads();
    s[t] += u;
    __syncthreads();
  }
  if (t < nblk) count[t * NB + b] = s[t] - v;   // exclusive within column
  if (t == 255) btot[b] = s[255];
}

// --- stage 3: exclusive scan of 512 bucket totals ---------------------------
__global__ __launch_bounds__(256) void k_btot_scan(const int* __restrict__ btot,
                                                   int* __restrict__ bucket_start,
                                                   int* __restrict__ row_start, int n) {
  __shared__ int a[NB];
  __shared__ int p[256];
  int t = threadIdx.x;
  a[t] = btot[t]; a[t + 256] = btot[t + 256];
  __syncthreads();
  int pv = a[2 * t] + a[2 * t + 1];
  p[t] = pv;
  __syncthreads();
  for (int off = 1; off < 256; off <<= 1) {
    int u = (t >= off) ? p[t - off] : 0;
    __syncthreads();
    p[t] += u;
    __syncthreads();
  }
  int pex = p[t] - pv;
  bucket_start[2 * t] = pex;
  bucket_start[2 * t + 1] = pex + a[2 * t];
  if (t == 255) {
    bucket_start[NB] = pex + pv;       // = E
    row_start[n] = pex + pv;           // = E
  }
}

// --- stage 4: LDS multisplit + coalesced copy-out to bucket-ordered pairs ---
__global__ __launch_bounds__(256) void k_scatter(const int* __restrict__ src,
                                                 const int* __restrict__ dst,
                                                 const int* __restrict__ colscan,
                                                 const int* __restrict__ bucket_start,
                                                 int2* __restrict__ pairs, int E) {
  __shared__ int gcur[NB];
  __shared__ int hist[NB];
  __shared__ int sstart[NB];
  __shared__ int cur[NB];
  __shared__ int p[256];
  __shared__ int2 stage[SUB];
  int t = threadIdx.x;
  for (int b = t; b < NB; b += 256)
    gcur[b] = bucket_start[b] + colscan[blockIdx.x * NB + b];
  int base = blockIdx.x * CHUNK;

  for (int sc = 0; sc < CHUNK / SUB; ++sc) {
    int sbase = base + sc * SUB;
    for (int b = t; b < NB; b += 256) hist[b] = 0;
    __syncthreads();
    int mys[SUB / 256], myd[SUB / 256], myb[SUB / 256];
#pragma unroll
    for (int i = 0; i < SUB / 256; ++i) {
      int idx = sbase + i * 256 + t;
      if (idx < E) {
        mys[i] = src[idx]; myd[i] = dst[idx];
        myb[i] = myd[i] / NPB;
        atomicAdd(&hist[myb[i]], 1);
      } else myb[i] = -1;
    }
    __syncthreads();
    // exclusive scan of hist[512] with 256 threads (pair trick)
    int pv = hist[2 * t] + hist[2 * t + 1];
    p[t] = pv;
    __syncthreads();
    for (int off = 1; off < 256; off <<= 1) {
      int u = (t >= off) ? p[t - off] : 0;
      __syncthreads();
      p[t] += u;
      __syncthreads();
    }
    int pex = p[t] - pv;
    sstart[2 * t] = pex;            cur[2 * t] = pex;
    sstart[2 * t + 1] = pex + hist[2 * t]; cur[2 * t + 1] = pex + hist[2 * t];
    __syncthreads();
    // insert into LDS staging (grouped by bucket)
#pragma unroll
    for (int i = 0; i < SUB / 256; ++i) {
      if (myb[i] >= 0) {
        int slot = atomicAdd(&cur[myb[i]], 1);
        stage[slot] = int2{mys[i], myd[i]};
      }
    }
    __syncthreads();
    // coalesced copy-out: consecutive slots of a segment -> consecutive global
    int total = sstart[NB - 1] + hist[NB - 1];
    for (int i = t; i < total; i += 256) {
      int2 pr = stage[i];
      int b = pr.y / NPB;
      pairs[gcur[b] + (i - sstart[b])] = pr;
    }
    __syncthreads();
    for (int b = t; b < NB; b += 256) gcur[b] += hist[b];
    __syncthreads();
  }
}

// --- stage 5: bucket -> CSR (+ row_start, dinv); single-owner 25KB window ---
__global__ __launch_bounds__(256) void k_bucket2csr(const int2* __restrict__ pairs,
                                                    const int* __restrict__ bucket_start,
                                                    int* __restrict__ row_start,
                                                    float* __restrict__ dinv,
                                                    int* __restrict__ csr_src, int n) {
  __shared__ int cnt[NPB];
  __shared__ int off[NPB];
  __shared__ int cur[NPB];
  int b = blockIdx.x, t = threadIdx.x;
  int bs = bucket_start[b], be = bucket_start[b + 1];
  int nodeBase = b * NPB;
  for (int i = t; i < NPB; i += 256) cnt[i] = 0;
  __syncthreads();
  for (int i = bs + t; i < be; i += 256)
    atomicAdd(&cnt[pairs[i].y - nodeBase], 1);
  __syncthreads();
  if (t == 0) {
    int run = 0;
    for (int i = 0; i < NPB; ++i) { off[i] = run; cur[i] = run; run += cnt[i]; }
  }
  __syncthreads();
  for (int i = t; i < NPB; i += 256) {
    int node = nodeBase + i;
    if (node < n) {
      row_start[node] = bs + off[i];
      dinv[node] = rsqrtf((float)(cnt[i] + 1));   // +1 self-loop
    }
  }
  for (int i = bs + t; i < be; i += 256) {
    int2 pr = pairs[i];
    int pos = bs + atomicAdd(&cur[pr.y - nodeBase], 1);
    csr_src[pos] = pr.x;
  }
}

// --- MFMA GEMM: [M,K] @ WT[N=128,K], epilogue: *dinv[row] -> bf16 -----------
// D layout (m89-verified): col = lane&15, row = (lane>>4)*4 + reg.
template <bool A_F32, int K>
__global__ __launch_bounds__(256) void k_gemm(const void* __restrict__ Av,
                                              const short* __restrict__ BT,
                                              const float* __restrict__ dinv,
                                              void* __restrict__ outv, int M) {
  int wave = threadIdx.x >> 6;
  int lane = threadIdx.x & 63;
  int rowBase = (blockIdx.x * 4 + wave) * 16;
  if (rowBase >= M) return;
  int r = lane & 15;
  int g = lane >> 4;
  int row = rowBase + r;

  f32x4 acc[8];
#pragma unroll
  for (int c = 0; c < 8; ++c) acc[c] = f32x4{0.f, 0.f, 0.f, 0.f};

  for (int k0 = 0; k0 < K; k0 += 32) {
    int kk = k0 + g * 8;
    bf16x8 afrag;
    if constexpr (A_F32) {
      const float* A = (const float*)Av;
      const f32x4* p = (const f32x4*)(A + (size_t)row * K + kk);
      f32x4 v0 = p[0], v1 = p[1];
      afrag[0] = f2bf(v0[0]); afrag[1] = f2bf(v0[1]);
      afrag[2] = f2bf(v0[2]); afrag[3] = f2bf(v0[3]);
      afrag[4] = f2bf(v1[0]); afrag[5] = f2bf(v1[1]);
      afrag[6] = f2bf(v1[2]); afrag[7] = f2bf(v1[3]);
    } else {
      const short* A = (const short*)Av;
      afrag = *(const bf16x8*)(A + (size_t)row * K + kk);
    }
#pragma unroll
    for (int c = 0; c < 8; ++c) {
      bf16x8 bfrag = *(const bf16x8*)(BT + (size_t)(c * 16 + r) * K + kk);
      acc[c] = __builtin_amdgcn_mfma_f32_16x16x32_bf16(afrag, bfrag, acc[c], 0, 0, 0);
    }
  }

#pragma unroll
  for (int c = 0; c < 8; ++c) {
    int cc = c * 16 + r;
#pragma unroll
    for (int j = 0; j < 4; ++j) {
      int rr = rowBase + g * 4 + j;
      ((short*)outv)[(size_t)rr * 128 + cc] = f2bf(acc[c][j] * dinv[rr]);
    }
  }
}

// --- fused final: out = x@WsT + h2@WfT + (bs+bf) ----------------------------
template <int K1, int K2>
__global__ __launch_bounds__(256) void k_gemm_dual(const float* __restrict__ A1,
                                                   const short* __restrict__ B1T,
                                                   const short* __restrict__ A2,
                                                   const short* __restrict__ B2T,
                                                   const float* __restrict__ bias1,
                                                   const float* __restrict__ bias2,
                                                   float* __restrict__ out, int M) {
  int wave = threadIdx.x >> 6;
  int lane = threadIdx.x & 63;
  int rowBase = (blockIdx.x * 4 + wave) * 16;
  if (rowBase >= M) return;
  int r = lane & 15;
  int g = lane >> 4;
  int row = rowBase + r;

  f32x4 acc[8];
#pragma unroll
  for (int c = 0; c < 8; ++c) acc[c] = f32x4{0.f, 0.f, 0.f, 0.f};

  for (int k0 = 0; k0 < K1; k0 += 32) {
    int kk = k0 + g * 8;
    const f32x4* p = (const f32x4*)(A1 + (size_t)row * K1 + kk);
    f32x4 v0 = p[0], v1 = p[1];
    bf16x8 afrag;
    afrag[0] = f2bf(v0[0]); afrag[1] = f2bf(v0[1]);
    afrag[2] = f2bf(v0[2]); afrag[3] = f2bf(v0[3]);
    afrag[4] = f2bf(v1[0]); afrag[5] = f2bf(v1[1]);
    afrag[6] = f2bf(v1[2]); afrag[7] = f2bf(v1[3]);
#pragma unroll
    for (int c = 0; c < 8; ++c) {
      bf16x8 bfrag = *(const bf16x8*)(B1T + (size_t)(c * 16 + r) * K1 + kk);
      acc[c] = __builtin_amdgcn_mfma_f32_16x16x32_bf16(afrag, bfrag, acc[c], 0, 0, 0);
    }
  }
  for (int k0 = 0; k0 < K2; k0 += 32) {
    int kk = k0 + g * 8;
    bf16x8 afrag = *(const bf16x8*)(A2 + (size_t)row * K2 + kk);
#pragma unroll
    for (int c = 0; c < 8; ++c) {
      bf16x8 bfrag = *(const bf16x8*)(B2T + (size_t)(c * 16 + r) * K2 + kk);
      acc[c] = __builtin_amdgcn_mfma_f32_16x16x32_bf16(afrag, bfrag, acc[c], 0, 0, 0);
    }
  }

#pragma unroll
  for (int c = 0; c < 8; ++c) {
    int cc = c * 16 + r;
    float b = bias1[cc] + bias2[cc];
#pragma unroll
    for (int j = 0; j < 4; ++j) {
      int rr = rowBase + g * 4 + j;
      out[(size_t)rr * 128 + cc] = acc[c][j] + b;
    }
  }
}

// --- per-node CSR gather-aggregate: 1 wave per node, 2 bf16 cols per lane ---
__global__ __launch_bounds__(256) void k_aggregate(const short* __restrict__ scaled,
                                                   const float* __restrict__ dinv,
                                                   const float* __restrict__ bias,
                                                   const int* __restrict__ row_start,
                                                   const int* __restrict__ csr_src,
                                                   short* __restrict__ hout, int n) {
  int node = blockIdx.x * 4 + (threadIdx.x >> 6);
  if (node >= n) return;
  int lane = threadIdx.x & 63;

  uint32_t u = ((const uint32_t*)(scaled + (size_t)node * 128))[lane];  // self loop
  float s0 = __uint_as_float(u << 16);
  float s1 = __uint_as_float(u & 0xffff0000u);

  int beg = row_start[node], end = row_start[node + 1];
  int j = beg;
  for (; j + 4 <= end; j += 4) {          // 4-wide for gather latency overlap
    int a = csr_src[j], b = csr_src[j + 1], c = csr_src[j + 2], d = csr_src[j + 3];
    uint32_t ua = ((const uint32_t*)(scaled + (size_t)a * 128))[lane];
    uint32_t ub = ((const uint32_t*)(scaled + (size_t)b * 128))[lane];
    uint32_t uc = ((const uint32_t*)(scaled + (size_t)c * 128))[lane];
    uint32_t ud = ((const uint32_t*)(scaled + (size_t)d * 128))[lane];
    s0 += __uint_as_float(ua << 16); s1 += __uint_as_float(ua & 0xffff0000u);
    s0 += __uint_as_float(ub << 16); s1 += __uint_as_float(ub & 0xffff0000u);
    s0 += __uint_as_float(uc << 16); s1 += __uint_as_float(uc & 0xffff0000u);
    s0 += __uint_as_float(ud << 16); s1 += __uint_as_float(ud & 0xffff0000u);
  }
  for (; j < end; ++j) {
    int a = csr_src[j];
    uint32_t ua = ((const uint32_t*)(scaled + (size_t)a * 128))[lane];
    s0 += __uint_as_float(ua << 16); s1 += __uint_as_float(ua & 0xffff0000u);
  }

  float di = dinv[node];
  float h0 = fmaxf(fmaf(s0, di, bias[lane * 2]), 0.f);
  float h1 = fmaxf(fmaf(s1, di, bias[lane * 2 + 1]), 0.f);
  uint32_t o = (uint32_t)(uint16_t)f2bf(h0) | ((uint32_t)(uint16_t)f2bf(h1) << 16);
  ((uint32_t*)(hout + (size_t)node * 128))[lane] = o;
}

extern "C" void kernel_launch(void* const* d_in, const int* in_sizes, int n_in,
                              void* d_out, int out_size, void* d_ws, size_t ws_size,
                              hipStream_t stream) {
  const float* x  = (const float*)d_in[0];
  const int* ei   = (const int*)d_in[1];
  const float* W1 = (const float*)d_in[2];
  const float* b1 = (const float*)d_in[3];
  const float* W2 = (const float*)d_in[4];
  const float* b2 = (const float*)d_in[5];
  const float* Wsk = (const float*)d_in[6];
  const float* bsk = (const float*)d_in[7];
  const float* Wf = (const float*)d_in[8];
  const float* bf_ = (const float*)d_in[9];

  const int n = in_sizes[0] / 256;
  const int E = in_sizes[1] / 2;
  const int* src = ei;
  const int* dst = ei + E;

  char* p = (char*)d_ws;
  auto alloc = [&](size_t bytes) -> char* {
    char* r = p;
    p += (bytes + 255) & ~(size_t)255;
    return r;
  };
  // pairs (12.8MB, dead after k_bucket2csr) aliases scaled (written by GEMM-1)
  char* buf0       = alloc((size_t)E * 8);
  int2* pairs      = (int2*)buf0;
  short* scaled    = (short*)buf0;
  short* hbuf      = (short*)alloc((size_t)n * 128 * 2);  // 12.8 MB
  int* csr_src     = (int*)alloc((size_t)E * 4);          // 6.4 MB
  int* count       = (int*)alloc((size_t)256 * NB * 4);   // 512 KB max
  int* btot        = (int*)alloc(NB * 4);
  int* bucket_start= (int*)alloc((NB + 1) * 4);
  int* row_start   = (int*)alloc((size_t)(n + 1) * 4);
  float* dinv      = (float*)alloc((size_t)n * 4);
  short* W1T       = (short*)alloc(256 * 128 * 2);
  short* W2T       = (short*)alloc(128 * 128 * 2);
  short* WsT       = (short*)alloc(256 * 128 * 2);
  short* WfT       = (short*)alloc(128 * 128 * 2);

  const int nblk = (E + CHUNK - 1) / CHUNK;   // 196 for E=1.6M (<= 256)
  k_wtall<<<(98304 + 255) / 256, 256, 0, stream>>>(W1, W2, Wsk, Wf, W1T, W2T, WsT, WfT);
  k_count<<<nblk, 256, 0, stream>>>(dst, count, E);
  k_colscan<<<NB, 256, 0, stream>>>(count, btot, nblk);
  k_btot_scan<<<1, 256, 0, stream>>>(btot, bucket_start, row_start, n);
  k_scatter<<<nblk, 256, 0, stream>>>(src, dst, count, bucket_start, pairs, E);
  k_bucket2csr<<<NB, 256, 0, stream>>>(pairs, bucket_start, row_start, dinv, csr_src, n);

  const int gblocks = (n + 63) / 64;
  // layer 1
  k_gemm<true, 256><<<gblocks, 256, 0, stream>>>(x, W1T, dinv, scaled, n);
  k_aggregate<<<(n + 3) / 4, 256, 0, stream>>>(scaled, dinv, b1, row_start, csr_src, hbuf, n);
  // layer 2
  k_gemm<false, 128><<<gblocks, 256, 0, stream>>>(hbuf, W2T, dinv, scaled, n);
  k_aggregate<<<(n + 3) / 4, 256, 0, stream>>>(scaled, dinv, b2, row_start, csr_src, hbuf, n);
  // fused skip + final
  k_gemm_dual<256, 128><<<gblocks, 256, 0, stream>>>(x, WsT, hbuf, WfT, bsk, bf_, (float*)d_out, n);
}

// Round 4
// 272.910 us; speedup vs baseline: 2.1583x; 1.0958x over previous
//
#include <hip/hip_runtime.h>
#include <hip/hip_bf16.h>
#include <stdint.h>

// ---------------------------------------------------------------------------
// TrafficGNN: 2-layer GCN + skip, N=50000, E=1.6M, dims 256->128->128.
// R4 changes vs R3:
//  - k_aggregate: 4-wide -> 8-wide gather with index-batch prefetch
//    (latency-bound at 61.5us; double outstanding loads), launch_bounds(256,8).
//  - sort: CHUNK 8192->2048 (196->782 blocks), NPB 98->128 so bucket=dst>>7
//    (no int div) and pairs pack to ONE int (src<<7|local): write+read traffic
//    halved. colscan widened to 1024 threads. bucket2csr scan parallelized.
// ---------------------------------------------------------------------------

typedef __attribute__((ext_vector_type(8))) short bf16x8;
typedef __attribute__((ext_vector_type(4))) float f32x4;

#define NB 392        // dst buckets (392*128 = 50176 >= 50000)
#define NPB 128       // nodes per bucket (pow2: bucket = dst>>7)
#define CHUNK 2048    // edges per k_count/k_scatter block

__device__ __forceinline__ short f2bf(float f) {
  uint32_t u = __float_as_uint(f);
  u += 0x7fffu + ((u >> 16) & 1u);   // round-to-nearest-even
  return (short)(u >> 16);
}

// --- fused weight transpose+cast: W[K][N] f32 -> WT[N][K] bf16 --------------
__global__ void k_wtall(const float* __restrict__ W1, const float* __restrict__ W2,
                        const float* __restrict__ Ws, const float* __restrict__ Wf,
                        short* __restrict__ W1T, short* __restrict__ W2T,
                        short* __restrict__ WsT, short* __restrict__ WfT) {
  int i = blockIdx.x * blockDim.x + threadIdx.x;
  const float* W; short* WT; int K, off;
  if (i < 32768)      { W = W1; WT = W1T; K = 256; off = 0; }
  else if (i < 49152) { W = W2; WT = W2T; K = 128; off = 32768; }
  else if (i < 81920) { W = Ws; WT = WsT; K = 256; off = 49152; }
  else if (i < 98304) { W = Wf; WT = WfT; K = 128; off = 81920; }
  else return;
  int j = i - off;
  int k = j >> 7, n = j & 127;            // N = 128 always
  WT[n * K + k] = f2bf(W[j]);
}

// --- stage 1: per-chunk bucket histogram ------------------------------------
__global__ __launch_bounds__(256) void k_count(const int* __restrict__ dst,
                                               int* __restrict__ count, int E) {
  __shared__ int h[512];
  int t = threadIdx.x;
  h[t] = 0; h[t + 256] = 0;
  __syncthreads();
  int base = blockIdx.x * CHUNK;
#pragma unroll
  for (int i = 0; i < CHUNK / 256; ++i) {
    int idx = base + i * 256 + t;
    if (idx < E) atomicAdd(&h[dst[idx] >> 7], 1);
  }
  __syncthreads();
  if (t < NB) count[blockIdx.x * NB + t] = h[t];
  if (t + 256 < NB) count[blockIdx.x * NB + t + 256] = h[t + 256];
}

// --- stage 2: per-bucket exclusive scan over chunks (nblk <= 1024) ----------
__global__ __launch_bounds__(1024) void k_colscan(int* __restrict__ count,
                                                  int* __restrict__ btot, int nblk) {
  __shared__ int s[1024];
  int t = threadIdx.x, b = blockIdx.x;
  int v = (t < nblk) ? count[t * NB + b] : 0;
  s[t] = v;
  __syncthreads();
  for (int off = 1; off < 1024; off <<= 1) {
    int u = (t >= off) ? s[t - off] : 0;
    __syncthreads();
    s[t] += u;
    __syncthreads();
  }
  if (t < nblk) count[t * NB + b] = s[t] - v;   // exclusive within column
  if (t == 1023) btot[b] = s[1023];
}

// --- stage 3: exclusive scan of NB bucket totals ----------------------------
__global__ __launch_bounds__(256) void k_btot_scan(const int* __restrict__ btot,
                                                   int* __restrict__ bucket_start,
                                                   int* __restrict__ row_start, int n) {
  __shared__ int a[512];
  __shared__ int p[256];
  int t = threadIdx.x;
  a[t] = (t < NB) ? btot[t] : 0;
  a[t + 256] = (t + 256 < NB) ? btot[t + 256] : 0;
  __syncthreads();
  int pv = a[2 * t] + a[2 * t + 1];
  p[t] = pv;
  __syncthreads();
  for (int off = 1; off < 256; off <<= 1) {
    int u = (t >= off) ? p[t - off] : 0;
    __syncthreads();
    p[t] += u;
    __syncthreads();
  }
  int pex = p[t] - pv;
  if (2 * t < NB + 1) bucket_start[2 * t] = pex;
  if (2 * t + 1 < NB + 1) bucket_start[2 * t + 1] = pex + a[2 * t];
  if (t == 255) row_start[n] = p[255];   // = E
}

// --- stage 4: LDS multisplit + coalesced copy-out (packed int) --------------
__global__ __launch_bounds__(256) void k_scatter(const int* __restrict__ src,
                                                 const int* __restrict__ dst,
                                                 const int* __restrict__ colscan,
                                                 const int* __restrict__ bucket_start,
                                                 int* __restrict__ pairs, int E) {
  __shared__ int gcur[NB];
  __shared__ int hist[512];
  __shared__ int sstart[512];
  __shared__ int cur[512];
  __shared__ int p[256];
  __shared__ int2 stage[CHUNK];
  __shared__ int tot;
  int t = threadIdx.x;
  if (t < NB) gcur[t] = bucket_start[t] + colscan[blockIdx.x * NB + t];
  if (t + 256 < NB) gcur[t + 256] = bucket_start[t + 256] + colscan[blockIdx.x * NB + t + 256];
  hist[t] = 0; hist[t + 256] = 0;
  __syncthreads();
  int base = blockIdx.x * CHUNK;
  int mys[CHUNK / 256], myd[CHUNK / 256];
#pragma unroll
  for (int i = 0; i < CHUNK / 256; ++i) {
    int idx = base + i * 256 + t;
    if (idx < E) {
      mys[i] = src[idx]; myd[i] = dst[idx];
      atomicAdd(&hist[myd[i] >> 7], 1);
    } else myd[i] = -1;
  }
  __syncthreads();
  // exclusive scan of hist[512] with 256 threads (pair trick)
  int pv = hist[2 * t] + hist[2 * t + 1];
  p[t] = pv;
  __syncthreads();
  for (int off = 1; off < 256; off <<= 1) {
    int u = (t >= off) ? p[t - off] : 0;
    __syncthreads();
    p[t] += u;
    __syncthreads();
  }
  int pex = p[t] - pv;
  sstart[2 * t] = pex;                   cur[2 * t] = pex;
  sstart[2 * t + 1] = pex + hist[2 * t]; cur[2 * t + 1] = pex + hist[2 * t];
  if (t == 255) tot = p[255];
  __syncthreads();
#pragma unroll
  for (int i = 0; i < CHUNK / 256; ++i) {
    if (myd[i] >= 0) {
      int slot = atomicAdd(&cur[myd[i] >> 7], 1);
      stage[slot] = int2{mys[i], myd[i]};
    }
  }
  __syncthreads();
  // coalesced copy-out: consecutive slots of a segment -> consecutive global
  int total = tot;
  for (int i = t; i < total; i += 256) {
    int2 pr = stage[i];
    int b = pr.y >> 7;
    pairs[gcur[b] + (i - sstart[b])] = (pr.x << 7) | (pr.y & 127);
  }
}

// --- stage 5: bucket -> CSR (+ row_start, dinv); 16KB single-owner window ---
__global__ __launch_bounds__(256) void k_bucket2csr(const int* __restrict__ pairs,
                                                    const int* __restrict__ bucket_start,
                                                    int* __restrict__ row_start,
                                                    float* __restrict__ dinv,
                                                    int* __restrict__ csr_src, int n) {
  __shared__ int cnt[NPB];
  __shared__ int scn[NPB];
  __shared__ int cur[NPB];
  int b = blockIdx.x, t = threadIdx.x;
  int bs = bucket_start[b], be = bucket_start[b + 1];
  int nodeBase = b << 7;
  if (t < NPB) cnt[t] = 0;
  __syncthreads();
  for (int i = bs + t; i < be; i += 256)
    atomicAdd(&cnt[pairs[i] & 127], 1);
  __syncthreads();
  int v = (t < NPB) ? cnt[t] : 0;
  if (t < NPB) scn[t] = v;
  __syncthreads();
  for (int off = 1; off < NPB; off <<= 1) {
    int u = (t >= off && t < NPB) ? scn[t - off] : 0;
    __syncthreads();
    if (t < NPB) scn[t] += u;
    __syncthreads();
  }
  if (t < NPB) {
    int ex = scn[t] - v;
    cur[t] = ex;
    int node = nodeBase + t;
    if (node < n) {
      row_start[node] = bs + ex;
      dinv[node] = rsqrtf((float)(v + 1));   // +1 self-loop
    }
  }
  __syncthreads();
  for (int i = bs + t; i < be; i += 256) {
    int packed = pairs[i];
    int pos = bs + atomicAdd(&cur[packed & 127], 1);
    csr_src[pos] = packed >> 7;
  }
}

// --- MFMA GEMM: [M,K] @ WT[N=128,K], epilogue: *dinv[row] -> bf16 -----------
// D layout (m89-verified): col = lane&15, row = (lane>>4)*4 + reg.
template <bool A_F32, int K>
__global__ __launch_bounds__(256) void k_gemm(const void* __restrict__ Av,
                                              const short* __restrict__ BT,
                                              const float* __restrict__ dinv,
                                              void* __restrict__ outv, int M) {
  int wave = threadIdx.x >> 6;
  int lane = threadIdx.x & 63;
  int rowBase = (blockIdx.x * 4 + wave) * 16;
  if (rowBase >= M) return;
  int r = lane & 15;
  int g = lane >> 4;
  int row = rowBase + r;

  f32x4 acc[8];
#pragma unroll
  for (int c = 0; c < 8; ++c) acc[c] = f32x4{0.f, 0.f, 0.f, 0.f};

  for (int k0 = 0; k0 < K; k0 += 32) {
    int kk = k0 + g * 8;
    bf16x8 afrag;
    if constexpr (A_F32) {
      const float* A = (const float*)Av;
      const f32x4* p = (const f32x4*)(A + (size_t)row * K + kk);
      f32x4 v0 = p[0], v1 = p[1];
      afrag[0] = f2bf(v0[0]); afrag[1] = f2bf(v0[1]);
      afrag[2] = f2bf(v0[2]); afrag[3] = f2bf(v0[3]);
      afrag[4] = f2bf(v1[0]); afrag[5] = f2bf(v1[1]);
      afrag[6] = f2bf(v1[2]); afrag[7] = f2bf(v1[3]);
    } else {
      const short* A = (const short*)Av;
      afrag = *(const bf16x8*)(A + (size_t)row * K + kk);
    }
#pragma unroll
    for (int c = 0; c < 8; ++c) {
      bf16x8 bfrag = *(const bf16x8*)(BT + (size_t)(c * 16 + r) * K + kk);
      acc[c] = __builtin_amdgcn_mfma_f32_16x16x32_bf16(afrag, bfrag, acc[c], 0, 0, 0);
    }
  }

#pragma unroll
  for (int c = 0; c < 8; ++c) {
    int cc = c * 16 + r;
#pragma unroll
    for (int j = 0; j < 4; ++j) {
      int rr = rowBase + g * 4 + j;
      ((short*)outv)[(size_t)rr * 128 + cc] = f2bf(acc[c][j] * dinv[rr]);
    }
  }
}

// --- fused final: out = x@WsT + h2@WfT + (bs+bf) ----------------------------
template <int K1, int K2>
__global__ __launch_bounds__(256) void k_gemm_dual(const float* __restrict__ A1,
                                                   const short* __restrict__ B1T,
                                                   const short* __restrict__ A2,
                                                   const short* __restrict__ B2T,
                                                   const float* __restrict__ bias1,
                                                   const float* __restrict__ bias2,
                                                   float* __restrict__ out, int M) {
  int wave = threadIdx.x >> 6;
  int lane = threadIdx.x & 63;
  int rowBase = (blockIdx.x * 4 + wave) * 16;
  if (rowBase >= M) return;
  int r = lane & 15;
  int g = lane >> 4;
  int row = rowBase + r;

  f32x4 acc[8];
#pragma unroll
  for (int c = 0; c < 8; ++c) acc[c] = f32x4{0.f, 0.f, 0.f, 0.f};

  for (int k0 = 0; k0 < K1; k0 += 32) {
    int kk = k0 + g * 8;
    const f32x4* p = (const f32x4*)(A1 + (size_t)row * K1 + kk);
    f32x4 v0 = p[0], v1 = p[1];
    bf16x8 afrag;
    afrag[0] = f2bf(v0[0]); afrag[1] = f2bf(v0[1]);
    afrag[2] = f2bf(v0[2]); afrag[3] = f2bf(v0[3]);
    afrag[4] = f2bf(v1[0]); afrag[5] = f2bf(v1[1]);
    afrag[6] = f2bf(v1[2]); afrag[7] = f2bf(v1[3]);
#pragma unroll
    for (int c = 0; c < 8; ++c) {
      bf16x8 bfrag = *(const bf16x8*)(B1T + (size_t)(c * 16 + r) * K1 + kk);
      acc[c] = __builtin_amdgcn_mfma_f32_16x16x32_bf16(afrag, bfrag, acc[c], 0, 0, 0);
    }
  }
  for (int k0 = 0; k0 < K2; k0 += 32) {
    int kk = k0 + g * 8;
    bf16x8 afrag = *(const bf16x8*)(A2 + (size_t)row * K2 + kk);
#pragma unroll
    for (int c = 0; c < 8; ++c) {
      bf16x8 bfrag = *(const bf16x8*)(B2T + (size_t)(c * 16 + r) * K2 + kk);
      acc[c] = __builtin_amdgcn_mfma_f32_16x16x32_bf16(afrag, bfrag, acc[c], 0, 0, 0);
    }
  }

#pragma unroll
  for (int c = 0; c < 8; ++c) {
    int cc = c * 16 + r;
    float b = bias1[cc] + bias2[cc];
#pragma unroll
    for (int j = 0; j < 4; ++j) {
      int rr = rowBase + g * 4 + j;
      out[(size_t)rr * 128 + cc] = acc[c][j] + b;
    }
  }
}

// --- per-node CSR gather: 8-wide, index-batch prefetch, 8 waves/SIMD --------
__global__ __launch_bounds__(256, 8) void k_aggregate(const short* __restrict__ scaled,
                                                      const float* __restrict__ dinv,
                                                      const float* __restrict__ bias,
                                                      const int* __restrict__ row_start,
                                                      const int* __restrict__ csr_src,
                                                      short* __restrict__ hout, int n) {
  int node = blockIdx.x * 4 + (threadIdx.x >> 6);
  if (node >= n) return;
  int lane = threadIdx.x & 63;
  const uint32_t* __restrict__ su = (const uint32_t*)scaled;

  uint32_t u = su[(uint32_t)node * 64u + lane];   // self loop
  float s0 = __uint_as_float(u << 16);
  float s1 = __uint_as_float(u & 0xffff0000u);

  int beg = row_start[node], end = row_start[node + 1];
  int deg = end - beg;
  int nfull = deg & ~7;
  int j = beg;
  if (nfull) {
    uint32_t offv[8];
#pragma unroll
    for (int q = 0; q < 8; ++q) offv[q] = (uint32_t)csr_src[beg + q] * 64u + lane;
    for (int base = 8;; base += 8) {
      uint32_t v[8];
#pragma unroll
      for (int q = 0; q < 8; ++q) v[q] = su[offv[q]];
      bool more = (base < nfull);
      if (more) {
#pragma unroll
        for (int q = 0; q < 8; ++q) offv[q] = (uint32_t)csr_src[beg + base + q] * 64u + lane;
      }
#pragma unroll
      for (int q = 0; q < 8; ++q) {
        s0 += __uint_as_float(v[q] << 16);
        s1 += __uint_as_float(v[q] & 0xffff0000u);
      }
      if (!more) break;
    }
    j = beg + nfull;
  }
  for (; j < end; ++j) {
    uint32_t ua = su[(uint32_t)csr_src[j] * 64u + lane];
    s0 += __uint_as_float(ua << 16);
    s1 += __uint_as_float(ua & 0xffff0000u);
  }

  float di = dinv[node];
  float h0 = fmaxf(fmaf(s0, di, bias[lane * 2]), 0.f);
  float h1 = fmaxf(fmaf(s1, di, bias[lane * 2 + 1]), 0.f);
  uint32_t o = (uint32_t)(uint16_t)f2bf(h0) | ((uint32_t)(uint16_t)f2bf(h1) << 16);
  ((uint32_t*)hout)[(uint32_t)node * 64u + lane] = o;
}

extern "C" void kernel_launch(void* const* d_in, const int* in_sizes, int n_in,
                              void* d_out, int out_size, void* d_ws, size_t ws_size,
                              hipStream_t stream) {
  const float* x  = (const float*)d_in[0];
  const int* ei   = (const int*)d_in[1];
  const float* W1 = (const float*)d_in[2];
  const float* b1 = (const float*)d_in[3];
  const float* W2 = (const float*)d_in[4];
  const float* b2 = (const float*)d_in[5];
  const float* Wsk = (const float*)d_in[6];
  const float* bsk = (const float*)d_in[7];
  const float* Wf = (const float*)d_in[8];
  const float* bf_ = (const float*)d_in[9];

  const int n = in_sizes[0] / 256;
  const int E = in_sizes[1] / 2;
  const int* src = ei;
  const int* dst = ei + E;

  char* p = (char*)d_ws;
  auto alloc = [&](size_t bytes) -> char* {
    char* r = p;
    p += (bytes + 255) & ~(size_t)255;
    return r;
  };
  // pairs (6.4MB packed, dead after k_bucket2csr) aliases scaled
  char* buf0       = alloc((size_t)n * 128 * 2);          // 12.8 MB
  int* pairs       = (int*)buf0;
  short* scaled    = (short*)buf0;
  short* hbuf      = (short*)alloc((size_t)n * 128 * 2);  // 12.8 MB
  int* csr_src     = (int*)alloc((size_t)E * 4);          // 6.4 MB
  int* count       = (int*)alloc((size_t)1024 * NB * 4);  // 1.6 MB max
  int* btot        = (int*)alloc(NB * 4);
  int* bucket_start= (int*)alloc((NB + 1) * 4);
  int* row_start   = (int*)alloc((size_t)(n + 1) * 4);
  float* dinv      = (float*)alloc((size_t)n * 4);
  short* W1T       = (short*)alloc(256 * 128 * 2);
  short* W2T       = (short*)alloc(128 * 128 * 2);
  short* WsT       = (short*)alloc(256 * 128 * 2);
  short* WfT       = (short*)alloc(128 * 128 * 2);

  const int nblk = (E + CHUNK - 1) / CHUNK;   // 782 for E=1.6M (<= 1024)
  k_wtall<<<(98304 + 255) / 256, 256, 0, stream>>>(W1, W2, Wsk, Wf, W1T, W2T, WsT, WfT);
  k_count<<<nblk, 256, 0, stream>>>(dst, count, E);
  k_colscan<<<NB, 1024, 0, stream>>>(count, btot, nblk);
  k_btot_scan<<<1, 256, 0, stream>>>(btot, bucket_start, row_start, n);
  k_scatter<<<nblk, 256, 0, stream>>>(src, dst, count, bucket_start, pairs, E);
  k_bucket2csr<<<NB, 256, 0, stream>>>(pairs, bucket_start, row_start, dinv, csr_src, n);

  const int gblocks = (n + 63) / 64;
  // layer 1
  k_gemm<true, 256><<<gblocks, 256, 0, stream>>>(x, W1T, dinv, scaled, n);
  k_aggregate<<<(n + 3) / 4, 256, 0, stream>>>(scaled, dinv, b1, row_start, csr_src, hbuf, n);
  // layer 2
  k_gemm<false, 128><<<gblocks, 256, 0, stream>>>(hbuf, W2T, dinv, scaled, n);
  k_aggregate<<<(n + 3) / 4, 256, 0, stream>>>(scaled, dinv, b2, row_start, csr_src, hbuf, n);
  // fused skip + final
  k_gemm_dual<256, 128><<<gblocks, 256, 0, stream>>>(x, WsT, hbuf, WfT, bsk, bf_, (float*)d_out, n);
}

// Round 5
// 216.234 us; speedup vs baseline: 2.7240x; 1.2621x over previous
//
#include <hip/hip_runtime.h>
#include <hip/hip_bf16.h>
#include <stdint.h>

// ---------------------------------------------------------------------------
// TrafficGNN: 2-layer GCN + skip, N=50000, E=1.6M, dims 256->128->128.
// R5 changes vs R4:
//  - GEMMs rewritten (were latency-bound: MfmaUtil 3%, B re-read from global
//    every K-step). Now: B staged in LDS as 32KB XOR-swizzled K-panels
//    (conflict-free ds_read_b128), 4 waves x 32 rows = 128 rows/block,
//    16 MFMA per K-step per wave, only A comes from global in the loop.
//    k_gemm_dual runs 3 panels (2x W1T, 1x W2T) through the same buffer.
//  - sort + aggregate unchanged.
// ---------------------------------------------------------------------------

typedef __attribute__((ext_vector_type(8))) short bf16x8;
typedef __attribute__((ext_vector_type(4))) float f32x4;

#define NB 392        // dst buckets (392*128 = 50176 >= 50000)
#define NPB 128       // nodes per bucket (pow2: bucket = dst>>7)
#define CHUNK 2048    // edges per k_count/k_scatter block

__device__ __forceinline__ short f2bf(float f) {
  uint32_t u = __float_as_uint(f);
  u += 0x7fffu + ((u >> 16) & 1u);   // round-to-nearest-even
  return (short)(u >> 16);
}

// --- fused weight transpose+cast: W[K][N] f32 -> WT[N][K] bf16 --------------
__global__ void k_wtall(const float* __restrict__ W1, const float* __restrict__ W2,
                        const float* __restrict__ Ws, const float* __restrict__ Wf,
                        short* __restrict__ W1T, short* __restrict__ W2T,
                        short* __restrict__ WsT, short* __restrict__ WfT) {
  int i = blockIdx.x * blockDim.x + threadIdx.x;
  const float* W; short* WT; int K, off;
  if (i < 32768)      { W = W1; WT = W1T; K = 256; off = 0; }
  else if (i < 49152) { W = W2; WT = W2T; K = 128; off = 32768; }
  else if (i < 81920) { W = Ws; WT = WsT; K = 256; off = 49152; }
  else if (i < 98304) { W = Wf; WT = WfT; K = 128; off = 81920; }
  else return;
  int j = i - off;
  int k = j >> 7, n = j & 127;            // N = 128 always
  WT[n * K + k] = f2bf(W[j]);
}

// --- stage 1: per-chunk bucket histogram ------------------------------------
__global__ __launch_bounds__(256) void k_count(const int* __restrict__ dst,
                                               int* __restrict__ count, int E) {
  __shared__ int h[512];
  int t = threadIdx.x;
  h[t] = 0; h[t + 256] = 0;
  __syncthreads();
  int base = blockIdx.x * CHUNK;
#pragma unroll
  for (int i = 0; i < CHUNK / 256; ++i) {
    int idx = base + i * 256 + t;
    if (idx < E) atomicAdd(&h[dst[idx] >> 7], 1);
  }
  __syncthreads();
  if (t < NB) count[blockIdx.x * NB + t] = h[t];
  if (t + 256 < NB) count[blockIdx.x * NB + t + 256] = h[t + 256];
}

// --- stage 2: per-bucket exclusive scan over chunks (nblk <= 1024) ----------
__global__ __launch_bounds__(1024) void k_colscan(int* __restrict__ count,
                                                  int* __restrict__ btot, int nblk) {
  __shared__ int s[1024];
  int t = threadIdx.x, b = blockIdx.x;
  int v = (t < nblk) ? count[t * NB + b] : 0;
  s[t] = v;
  __syncthreads();
  for (int off = 1; off < 1024; off <<= 1) {
    int u = (t >= off) ? s[t - off] : 0;
    __syncthreads();
    s[t] += u;
    __syncthreads();
  }
  if (t < nblk) count[t * NB + b] = s[t] - v;   // exclusive within column
  if (t == 1023) btot[b] = s[1023];
}

// --- stage 3: exclusive scan of NB bucket totals ----------------------------
__global__ __launch_bounds__(256) void k_btot_scan(const int* __restrict__ btot,
                                                   int* __restrict__ bucket_start,
                                                   int* __restrict__ row_start, int n) {
  __shared__ int a[512];
  __shared__ int p[256];
  int t = threadIdx.x;
  a[t] = (t < NB) ? btot[t] : 0;
  a[t + 256] = (t + 256 < NB) ? btot[t + 256] : 0;
  __syncthreads();
  int pv = a[2 * t] + a[2 * t + 1];
  p[t] = pv;
  __syncthreads();
  for (int off = 1; off < 256; off <<= 1) {
    int u = (t >= off) ? p[t - off] : 0;
    __syncthreads();
    p[t] += u;
    __syncthreads();
  }
  int pex = p[t] - pv;
  if (2 * t < NB + 1) bucket_start[2 * t] = pex;
  if (2 * t + 1 < NB + 1) bucket_start[2 * t + 1] = pex + a[2 * t];
  if (t == 255) row_start[n] = p[255];   // = E
}

// --- stage 4: LDS multisplit + coalesced copy-out (packed int) --------------
__global__ __launch_bounds__(256) void k_scatter(const int* __restrict__ src,
                                                 const int* __restrict__ dst,
                                                 const int* __restrict__ colscan,
                                                 const int* __restrict__ bucket_start,
                                                 int* __restrict__ pairs, int E) {
  __shared__ int gcur[NB];
  __shared__ int hist[512];
  __shared__ int sstart[512];
  __shared__ int cur[512];
  __shared__ int p[256];
  __shared__ int2 stage[CHUNK];
  __shared__ int tot;
  int t = threadIdx.x;
  if (t < NB) gcur[t] = bucket_start[t] + colscan[blockIdx.x * NB + t];
  if (t + 256 < NB) gcur[t + 256] = bucket_start[t + 256] + colscan[blockIdx.x * NB + t + 256];
  hist[t] = 0; hist[t + 256] = 0;
  __syncthreads();
  int base = blockIdx.x * CHUNK;
  int mys[CHUNK / 256], myd[CHUNK / 256];
#pragma unroll
  for (int i = 0; i < CHUNK / 256; ++i) {
    int idx = base + i * 256 + t;
    if (idx < E) {
      mys[i] = src[idx]; myd[i] = dst[idx];
      atomicAdd(&hist[myd[i] >> 7], 1);
    } else myd[i] = -1;
  }
  __syncthreads();
  // exclusive scan of hist[512] with 256 threads (pair trick)
  int pv = hist[2 * t] + hist[2 * t + 1];
  p[t] = pv;
  __syncthreads();
  for (int off = 1; off < 256; off <<= 1) {
    int u = (t >= off) ? p[t - off] : 0;
    __syncthreads();
    p[t] += u;
    __syncthreads();
  }
  int pex = p[t] - pv;
  sstart[2 * t] = pex;                   cur[2 * t] = pex;
  sstart[2 * t + 1] = pex + hist[2 * t]; cur[2 * t + 1] = pex + hist[2 * t];
  if (t == 255) tot = p[255];
  __syncthreads();
#pragma unroll
  for (int i = 0; i < CHUNK / 256; ++i) {
    if (myd[i] >= 0) {
      int slot = atomicAdd(&cur[myd[i] >> 7], 1);
      stage[slot] = int2{mys[i], myd[i]};
    }
  }
  __syncthreads();
  // coalesced copy-out: consecutive slots of a segment -> consecutive global
  int total = tot;
  for (int i = t; i < total; i += 256) {
    int2 pr = stage[i];
    int b = pr.y >> 7;
    pairs[gcur[b] + (i - sstart[b])] = (pr.x << 7) | (pr.y & 127);
  }
}

// --- stage 5: bucket -> CSR (+ row_start, dinv); 16KB single-owner window ---
__global__ __launch_bounds__(256) void k_bucket2csr(const int* __restrict__ pairs,
                                                    const int* __restrict__ bucket_start,
                                                    int* __restrict__ row_start,
                                                    float* __restrict__ dinv,
                                                    int* __restrict__ csr_src, int n) {
  __shared__ int cnt[NPB];
  __shared__ int scn[NPB];
  __shared__ int cur[NPB];
  int b = blockIdx.x, t = threadIdx.x;
  int bs = bucket_start[b], be = bucket_start[b + 1];
  int nodeBase = b << 7;
  if (t < NPB) cnt[t] = 0;
  __syncthreads();
  for (int i = bs + t; i < be; i += 256)
    atomicAdd(&cnt[pairs[i] & 127], 1);
  __syncthreads();
  int v = (t < NPB) ? cnt[t] : 0;
  if (t < NPB) scn[t] = v;
  __syncthreads();
  for (int off = 1; off < NPB; off <<= 1) {
    int u = (t >= off && t < NPB) ? scn[t - off] : 0;
    __syncthreads();
    if (t < NPB) scn[t] += u;
    __syncthreads();
  }
  if (t < NPB) {
    int ex = scn[t] - v;
    cur[t] = ex;
    int node = nodeBase + t;
    if (node < n) {
      row_start[node] = bs + ex;
      dinv[node] = rsqrtf((float)(v + 1));   // +1 self-loop
    }
  }
  __syncthreads();
  for (int i = bs + t; i < be; i += 256) {
    int packed = pairs[i];
    int pos = bs + atomicAdd(&cur[packed & 127], 1);
    csr_src[pos] = packed >> 7;
  }
}

// === LDS-staged panel GEMM ==================================================
// Block: 256 thr = 4 waves; wave owns 32 rows (2 x 16-row MFMA subtiles);
// block covers 128 rows. B-panel = 128 cols x 128 K-slice bf16 = 32KB in LDS,
// XOR-swizzled (byte ^= (nrow&7)<<4) -> conflict-free ds_read_b128 (2-way max).
// D layout (m89-verified): col = lane&15, row = (lane>>4)*4 + reg.

__device__ __forceinline__ void stage_panel(short* lB, const short* __restrict__ BT,
                                            int K, int p, int t) {
#pragma unroll
  for (int i = 0; i < 8; ++i) {
    int ch = t + i * 256;            // 2048 chunks of 8 shorts
    int nrow = ch >> 4;
    int kl = (ch & 15) << 3;         // local k (shorts)
    bf16x8 v = *(const bf16x8*)(BT + (size_t)nrow * K + p * 128 + kl);
    int byte = nrow * 256 + ((kl << 1) ^ ((nrow & 7) << 4));
    *(bf16x8*)((char*)lB + byte) = v;
  }
}

__device__ __forceinline__ bf16x8 lds_bfrag(const short* lB, int c, int r, int g, int k0) {
  int nrow = c * 16 + r;
  int byte = nrow * 256 + (((k0 + g * 8) << 1) ^ ((nrow & 7) << 4));
  return *(const bf16x8*)((const char*)lB + byte);
}

__device__ __forceinline__ bf16x8 load_a_f32(const float* A, int row, int K, int kidx) {
  const f32x4* p = (const f32x4*)(A + (size_t)row * K + kidx);
  f32x4 v0 = p[0], v1 = p[1];
  bf16x8 a;
  a[0] = f2bf(v0[0]); a[1] = f2bf(v0[1]); a[2] = f2bf(v0[2]); a[3] = f2bf(v0[3]);
  a[4] = f2bf(v1[0]); a[5] = f2bf(v1[1]); a[6] = f2bf(v1[2]); a[7] = f2bf(v1[3]);
  return a;
}

template <bool A_F32, int K>
__global__ __launch_bounds__(256, 4) void k_gemm(const void* __restrict__ Av,
                                                 const short* __restrict__ BT,
                                                 const float* __restrict__ dinv,
                                                 void* __restrict__ outv, int M) {
  __shared__ short lB[128 * 128];   // 32KB
  int t = threadIdx.x;
  int wave = t >> 6, lane = t & 63;
  int r = lane & 15, g = lane >> 4;
  int rowBase = blockIdx.x * 128 + wave * 32;

  f32x4 acc[2][8];
#pragma unroll
  for (int m = 0; m < 2; ++m)
#pragma unroll
    for (int c = 0; c < 8; ++c) acc[m][c] = f32x4{0.f, 0.f, 0.f, 0.f};

  int arow[2];
#pragma unroll
  for (int m = 0; m < 2; ++m) {
    int row = rowBase + m * 16 + r;
    arow[m] = (row < M) ? row : (M - 1);   // clamp: no early return (barriers)
  }

  for (int p = 0; p < K / 128; ++p) {
    stage_panel(lB, BT, K, p, t);
    __syncthreads();
#pragma unroll
    for (int k0 = 0; k0 < 128; k0 += 32) {
      int kidx = p * 128 + k0 + g * 8;
      bf16x8 af[2];
#pragma unroll
      for (int m = 0; m < 2; ++m) {
        if constexpr (A_F32) af[m] = load_a_f32((const float*)Av, arow[m], K, kidx);
        else af[m] = *(const bf16x8*)((const short*)Av + (size_t)arow[m] * K + kidx);
      }
#pragma unroll
      for (int c = 0; c < 8; ++c) {
        bf16x8 bfrag = lds_bfrag(lB, c, r, g, k0);
#pragma unroll
        for (int m = 0; m < 2; ++m)
          acc[m][c] = __builtin_amdgcn_mfma_f32_16x16x32_bf16(af[m], bfrag, acc[m][c], 0, 0, 0);
      }
    }
    __syncthreads();
  }

#pragma unroll
  for (int m = 0; m < 2; ++m)
#pragma unroll
    for (int j = 0; j < 4; ++j) {
      int rr = rowBase + m * 16 + g * 4 + j;
      if (rr < M) {
        float dv = dinv[rr];
#pragma unroll
        for (int c = 0; c < 8; ++c)
          ((short*)outv)[(size_t)rr * 128 + c * 16 + r] = f2bf(acc[m][c][j] * dv);
      }
    }
}

// --- fused final: out = x@WsT + h2@WfT + (bs+bf), 3 panels through 32KB -----
template <int K1, int K2>
__global__ __launch_bounds__(256, 4) void k_gemm_dual(const float* __restrict__ A1,
                                                      const short* __restrict__ B1T,
                                                      const short* __restrict__ A2,
                                                      const short* __restrict__ B2T,
                                                      const float* __restrict__ bias1,
                                                      const float* __restrict__ bias2,
                                                      float* __restrict__ out, int M) {
  __shared__ short lB[128 * 128];   // 32KB
  int t = threadIdx.x;
  int wave = t >> 6, lane = t & 63;
  int r = lane & 15, g = lane >> 4;
  int rowBase = blockIdx.x * 128 + wave * 32;

  f32x4 acc[2][8];
#pragma unroll
  for (int m = 0; m < 2; ++m)
#pragma unroll
    for (int c = 0; c < 8; ++c) acc[m][c] = f32x4{0.f, 0.f, 0.f, 0.f};

  int arow[2];
#pragma unroll
  for (int m = 0; m < 2; ++m) {
    int row = rowBase + m * 16 + r;
    arow[m] = (row < M) ? row : (M - 1);
  }

  for (int p = 0; p < K1 / 128; ++p) {
    stage_panel(lB, B1T, K1, p, t);
    __syncthreads();
#pragma unroll
    for (int k0 = 0; k0 < 128; k0 += 32) {
      int kidx = p * 128 + k0 + g * 8;
      bf16x8 af[2];
#pragma unroll
      for (int m = 0; m < 2; ++m) af[m] = load_a_f32(A1, arow[m], K1, kidx);
#pragma unroll
      for (int c = 0; c < 8; ++c) {
        bf16x8 bfrag = lds_bfrag(lB, c, r, g, k0);
#pragma unroll
        for (int m = 0; m < 2; ++m)
          acc[m][c] = __builtin_amdgcn_mfma_f32_16x16x32_bf16(af[m], bfrag, acc[m][c], 0, 0, 0);
      }
    }
    __syncthreads();
  }
  for (int p = 0; p < K2 / 128; ++p) {
    stage_panel(lB, B2T, K2, p, t);
    __syncthreads();
#pragma unroll
    for (int k0 = 0; k0 < 128; k0 += 32) {
      int kidx = p * 128 + k0 + g * 8;
      bf16x8 af[2];
#pragma unroll
      for (int m = 0; m < 2; ++m)
        af[m] = *(const bf16x8*)(A2 + (size_t)arow[m] * K2 + kidx);
#pragma unroll
      for (int c = 0; c < 8; ++c) {
        bf16x8 bfrag = lds_bfrag(lB, c, r, g, k0);
#pragma unroll
        for (int m = 0; m < 2; ++m)
          acc[m][c] = __builtin_amdgcn_mfma_f32_16x16x32_bf16(af[m], bfrag, acc[m][c], 0, 0, 0);
      }
    }
    __syncthreads();
  }

#pragma unroll
  for (int m = 0; m < 2; ++m)
#pragma unroll
    for (int j = 0; j < 4; ++j) {
      int rr = rowBase + m * 16 + g * 4 + j;
      if (rr < M) {
#pragma unroll
        for (int c = 0; c < 8; ++c) {
          int cc = c * 16 + r;
          out[(size_t)rr * 128 + cc] = acc[m][c][j] + bias1[cc] + bias2[cc];
        }
      }
    }
}

// --- per-node CSR gather: 8-wide, index-batch prefetch, 8 waves/SIMD --------
__global__ __launch_bounds__(256, 8) void k_aggregate(const short* __restrict__ scaled,
                                                      const float* __restrict__ dinv,
                                                      const float* __restrict__ bias,
                                                      const int* __restrict__ row_start,
                                                      const int* __restrict__ csr_src,
                                                      short* __restrict__ hout, int n) {
  int node = blockIdx.x * 4 + (threadIdx.x >> 6);
  if (node >= n) return;
  int lane = threadIdx.x & 63;
  const uint32_t* __restrict__ su = (const uint32_t*)scaled;

  uint32_t u = su[(uint32_t)node * 64u + lane];   // self loop
  float s0 = __uint_as_float(u << 16);
  float s1 = __uint_as_float(u & 0xffff0000u);

  int beg = row_start[node], end = row_start[node + 1];
  int deg = end - beg;
  int nfull = deg & ~7;
  int j = beg;
  if (nfull) {
    uint32_t offv[8];
#pragma unroll
    for (int q = 0; q < 8; ++q) offv[q] = (uint32_t)csr_src[beg + q] * 64u + lane;
    for (int base = 8;; base += 8) {
      uint32_t v[8];
#pragma unroll
      for (int q = 0; q < 8; ++q) v[q] = su[offv[q]];
      bool more = (base < nfull);
      if (more) {
#pragma unroll
        for (int q = 0; q < 8; ++q) offv[q] = (uint32_t)csr_src[beg + base + q] * 64u + lane;
      }
#pragma unroll
      for (int q = 0; q < 8; ++q) {
        s0 += __uint_as_float(v[q] << 16);
        s1 += __uint_as_float(v[q] & 0xffff0000u);
      }
      if (!more) break;
    }
    j = beg + nfull;
  }
  for (; j < end; ++j) {
    uint32_t ua = su[(uint32_t)csr_src[j] * 64u + lane];
    s0 += __uint_as_float(ua << 16);
    s1 += __uint_as_float(ua & 0xffff0000u);
  }

  float di = dinv[node];
  float h0 = fmaxf(fmaf(s0, di, bias[lane * 2]), 0.f);
  float h1 = fmaxf(fmaf(s1, di, bias[lane * 2 + 1]), 0.f);
  uint32_t o = (uint32_t)(uint16_t)f2bf(h0) | ((uint32_t)(uint16_t)f2bf(h1) << 16);
  ((uint32_t*)hout)[(uint32_t)node * 64u + lane] = o;
}

extern "C" void kernel_launch(void* const* d_in, const int* in_sizes, int n_in,
                              void* d_out, int out_size, void* d_ws, size_t ws_size,
                              hipStream_t stream) {
  const float* x  = (const float*)d_in[0];
  const int* ei   = (const int*)d_in[1];
  const float* W1 = (const float*)d_in[2];
  const float* b1 = (const float*)d_in[3];
  const float* W2 = (const float*)d_in[4];
  const float* b2 = (const float*)d_in[5];
  const float* Wsk = (const float*)d_in[6];
  const float* bsk = (const float*)d_in[7];
  const float* Wf = (const float*)d_in[8];
  const float* bf_ = (const float*)d_in[9];

  const int n = in_sizes[0] / 256;
  const int E = in_sizes[1] / 2;
  const int* src = ei;
  const int* dst = ei + E;

  char* p = (char*)d_ws;
  auto alloc = [&](size_t bytes) -> char* {
    char* r = p;
    p += (bytes + 255) & ~(size_t)255;
    return r;
  };
  // pairs (6.4MB packed, dead after k_bucket2csr) aliases scaled
  char* buf0       = alloc((size_t)n * 128 * 2);          // 12.8 MB
  int* pairs       = (int*)buf0;
  short* scaled    = (short*)buf0;
  short* hbuf      = (short*)alloc((size_t)n * 128 * 2);  // 12.8 MB
  int* csr_src     = (int*)alloc((size_t)E * 4);          // 6.4 MB
  int* count       = (int*)alloc((size_t)1024 * NB * 4);  // 1.6 MB max
  int* btot        = (int*)alloc(NB * 4);
  int* bucket_start= (int*)alloc((NB + 1) * 4);
  int* row_start   = (int*)alloc((size_t)(n + 1) * 4);
  float* dinv      = (float*)alloc((size_t)n * 4);
  short* W1T       = (short*)alloc(256 * 128 * 2);
  short* W2T       = (short*)alloc(128 * 128 * 2);
  short* WsT       = (short*)alloc(256 * 128 * 2);
  short* WfT       = (short*)alloc(128 * 128 * 2);

  const int nblk = (E + CHUNK - 1) / CHUNK;   // 782 for E=1.6M (<= 1024)
  k_wtall<<<(98304 + 255) / 256, 256, 0, stream>>>(W1, W2, Wsk, Wf, W1T, W2T, WsT, WfT);
  k_count<<<nblk, 256, 0, stream>>>(dst, count, E);
  k_colscan<<<NB, 1024, 0, stream>>>(count, btot, nblk);
  k_btot_scan<<<1, 256, 0, stream>>>(btot, bucket_start, row_start, n);
  k_scatter<<<nblk, 256, 0, stream>>>(src, dst, count, bucket_start, pairs, E);
  k_bucket2csr<<<NB, 256, 0, stream>>>(pairs, bucket_start, row_start, dinv, csr_src, n);

  const int gblocks = (n + 127) / 128;   // 391
  // layer 1
  k_gemm<true, 256><<<gblocks, 256, 0, stream>>>(x, W1T, dinv, scaled, n);
  k_aggregate<<<(n + 3) / 4, 256, 0, stream>>>(scaled, dinv, b1, row_start, csr_src, hbuf, n);
  // layer 2
  k_gemm<false, 128><<<gblocks, 256, 0, stream>>>(hbuf, W2T, dinv, scaled, n);
  k_aggregate<<<(n + 3) / 4, 256, 0, stream>>>(scaled, dinv, b2, row_start, csr_src, hbuf, n);
  // fused skip + final
  k_gemm_dual<256, 128><<<gblocks, 256, 0, stream>>>(x, WsT, hbuf, WfT, bsk, bf_, (float*)d_out, n);
}